// Round 4
// baseline (367.002 us; speedup 1.0000x reference)
//
#include <hip/hip_runtime.h>
#include <math.h>

// Problem constants (from reference)
#define NM       16     // total SH components l=0..3
#define NQ       32     // N_PSEUDO * N_MAX
#define CUT      5.0f
#define CAP      96     // per-node edge bucket capacity (max degree ~45 here)
#define CHUNK    16     // edges staged in LDS per iteration (per wave)
#define SLOT     52     // floats per edge slot: 16 Y + 32 W + 4 pad (16B-aligned)

typedef float v4f __attribute__((ext_vector_type(4)));

// ---------------------------------------------------------------------------
// Kernel 1: bin edges by destination node i, filtering r >= CUT (zero fcut).
// Stores {dx,dy,dz,species_j} per passing edge. One int atomic per edge.
// ---------------------------------------------------------------------------
__global__ __launch_bounds__(256) void edge_bin_kernel(
    const float* __restrict__ pos,      // [N][3]
    const float* __restrict__ cells,    // [1][3][3]
    const int*   __restrict__ species,  // [N]
    const int*   __restrict__ eidx,     // [2][E]
    const int*   __restrict__ eshift,   // [E][3]
    int*         __restrict__ counts,   // [N]
    float4*      __restrict__ buckets,  // [N][CAP]
    int E)
{
    const int e = blockIdx.x * blockDim.x + threadIdx.x;
    if (e >= E) return;

    const int i = eidx[e];
    const int j = eidx[E + e];

    float dx = pos[3 * j + 0] - pos[3 * i + 0];
    float dy = pos[3 * j + 1] - pos[3 * i + 1];
    float dz = pos[3 * j + 2] - pos[3 * i + 2];

    const int sx = eshift[3 * e + 0];
    const int sy = eshift[3 * e + 1];
    const int sz = eshift[3 * e + 2];
    dx += (float)sx * cells[0] + (float)sy * cells[3] + (float)sz * cells[6];
    dy += (float)sx * cells[1] + (float)sy * cells[4] + (float)sz * cells[7];
    dz += (float)sx * cells[2] + (float)sy * cells[5] + (float)sz * cells[8];

    const float r2 = dx * dx + dy * dy + dz * dz;
    if (r2 >= CUT * CUT) return;        // fcut == 0 -> exact zero contribution

    const int slot = atomicAdd(&counts[i], 1);
    if (slot < CAP)
        buckets[(size_t)i * CAP + slot] =
            make_float4(dx, dy, dz, __int_as_float(species[j]));
}

// ---------------------------------------------------------------------------
// Kernel 2: wave-per-node fused kernel (4 nodes / 256-thread block).
// No __syncthreads anywhere: each wave owns a private LDS region; all LDS
// producer->consumer pairs are intra-wave (hardware lgkmcnt ordering).
// Phases: stage per-edge Y[16],W[32] in LDS -> register-accumulate c[16][32]
// (8 elems/lane) -> publish c to LDS -> power spectrum with contiguous
// nontemporal float4 wave-stores.
// ---------------------------------------------------------------------------
__global__ __launch_bounds__(256) void node_fused_kernel(
    const float4* __restrict__ buckets, // [N][CAP]
    const int*    __restrict__ counts,  // [N]
    const float*  __restrict__ semb,    // [4][4]
    const float*  __restrict__ mu,      // [8]
    const float*  __restrict__ sigma,   // [1]
    float*        __restrict__ out,     // [N][4096]
    int N)
{
    const int wid  = threadIdx.x >> 6;
    const int lane = threadIdx.x & 63;
    const int node = blockIdx.x * 4 + wid;
    if (node >= N) return;

    // per-wave private region: CHUNK edge slots of SLOT floats
    __shared__ __align__(16) float sE[4][CHUNK * SLOT];
    float* wbase = sE[wid];

    const float sig    = sigma[0];
    const float inv2s2 = -1.0f / (2.0f * sig * sig);

    const int cnt = min(counts[node], CAP);

    const int q = lane & 31;        // owned c column
    const int h = lane >> 5;        // owns rows h*8 .. h*8+7
    v4f acc0 = {0.f, 0.f, 0.f, 0.f};
    v4f acc1 = {0.f, 0.f, 0.f, 0.f};

    for (int base = 0; base < cnt; base += CHUNK) {
        const int nb = min(cnt - base, CHUNK);

        if (lane < nb) {
            const float4 b = buckets[(size_t)node * CAP + base + lane];
            const float dx = b.x, dy = b.y, dz = b.z;
            const float r2 = dx * dx + dy * dy + dz * dz + 1e-12f;
            const float r  = sqrtf(r2);
            const float invr = 1.0f / r;
            const float x = dx * invr, y = dy * invr, z = dz * invr;
            const float x2 = x * x, y2 = y * y, z2 = z * z;

            v4f* slot4 = (v4f*)(wbase + lane * SLOT);
            v4f Ya, Yb, Yc, Yd;
            Ya[0] = 0.28209479177387814f;
            Ya[1] = 0.4886025119029199f * y;
            Ya[2] = 0.4886025119029199f * z;
            Ya[3] = 0.4886025119029199f * x;
            Yb[0] = 1.0925484305920792f * x * y;
            Yb[1] = 1.0925484305920792f * y * z;
            Yb[2] = 0.31539156525252005f * (3.0f * z2 - 1.0f);
            Yb[3] = 1.0925484305920792f * x * z;
            Yc[0] = 0.5462742152960396f * (x2 - y2);
            Yc[1] = 0.5900435899266435f * y * (3.0f * x2 - y2);
            Yc[2] = 2.890611442640554f  * x * y * z;
            Yc[3] = 0.4570457994644658f * y * (5.0f * z2 - 1.0f);
            Yd[0] = 0.3731763325901154f * z * (5.0f * z2 - 3.0f);
            Yd[1] = 0.4570457994644658f * x * (5.0f * z2 - 1.0f);
            Yd[2] = 1.445305721320277f  * z * (x2 - y2);
            Yd[3] = 0.5900435899266435f * x * (x2 - 3.0f * y2);
            slot4[0] = Ya; slot4[1] = Yb; slot4[2] = Yc; slot4[3] = Yd;

            const float fcut = 0.5f * (__cosf(0.62831853071795864f * r) + 1.0f);
            float Rf[8];
#pragma unroll
            for (int n = 0; n < 8; ++n) {
                const float dr = r - mu[n];
                Rf[n] = __expf(dr * dr * inv2s2) * fcut;
            }
            const int sj = __float_as_int(b.w);
#pragma unroll
            for (int p = 0; p < 4; ++p) {
                const float ejp = semb[sj * 4 + p];
                v4f w0, w1;
#pragma unroll
                for (int n = 0; n < 4; ++n) { w0[n] = ejp * Rf[n]; w1[n] = ejp * Rf[4 + n]; }
                slot4[4 + 2 * p]     = w0;
                slot4[4 + 2 * p + 1] = w1;
            }
        }
        // intra-wave LDS write->read; lgkmcnt ordering, no barrier needed

        for (int e = 0; e < nb; ++e) {
            const float* ed = wbase + e * SLOT;
            const float w  = ed[16 + q];              // all 32 banks, 2-way: free
            const v4f y0 = *(const v4f*)(ed + h * 8);     // broadcast
            const v4f y1 = *(const v4f*)(ed + h * 8 + 4); // broadcast
            acc0 += y0 * w;
            acc1 += y1 * w;
        }
    }

    // publish c[16][32] into the wave region (accumulation is complete)
    float* wc = wbase;
#pragma unroll
    for (int jj = 0; jj < 4; ++jj) {
        wc[(h * 8 + jj) * NQ + q]     = acc0[jj];
        wc[(h * 8 + 4 + jj) * NQ + q] = acc1[jj];
    }

    // power spectrum: out4[node*1024 + l*256 + k*64 + lane]
    //   i4 = k*64+lane -> q2 = i4>>3, r4 = i4&7; float idx = 4*i4+v = q2*32+r
    const float cg[4] = {1.0f, 0.57735026918962576f,
                         0.44721359549995794f, 0.37796447300922723f};
    const v4f* wc4 = (const v4f*)wbase;
    const int  r4  = lane & 7;
    const int  qh  = lane >> 3;
    v4f* op = (v4f*)out + (size_t)node * 1024;

#pragma unroll
    for (int l = 0; l < 4; ++l) {
        const int mb = l * l;
        const int mc = 2 * l + 1;
        v4f bv[7];
#pragma unroll
        for (int m = 0; m < 7; ++m)
            if (m < mc) bv[m] = wc4[(mb + m) * 8 + r4];
        const float cgl = cg[l];
#pragma unroll
        for (int k = 0; k < 4; ++k) {
            const int q2 = k * 8 + qh;
            v4f s = {0.f, 0.f, 0.f, 0.f};
#pragma unroll
            for (int m = 0; m < 7; ++m)
                if (m < mc) s += wc[(mb + m) * NQ + q2] * bv[m];
            s *= cgl;
            __builtin_nontemporal_store(s, &op[l * 256 + k * 64 + lane]);
        }
    }
}

// ---------------------------------------------------------------------------
extern "C" void kernel_launch(void* const* d_in, const int* in_sizes, int n_in,
                              void* d_out, int out_size, void* d_ws, size_t ws_size,
                              hipStream_t stream) {
    const float* pos     = (const float*)d_in[0];
    const float* cells   = (const float*)d_in[1];
    const int*   species = (const int*)  d_in[2];
    const int*   eidx    = (const int*)  d_in[3];
    const int*   eshift  = (const int*)  d_in[4];
    const float* semb    = (const float*)d_in[5];
    const float* mu      = (const float*)d_in[6];
    const float* sigma   = (const float*)d_in[7];
    float*       out     = (float*)d_out;

    const int N = in_sizes[0] / 3;
    const int E = in_sizes[3] / 2;

    float4* buckets = (float4*)d_ws;                         // [N][CAP] x 16B
    const size_t bucket_bytes = (size_t)N * CAP * sizeof(float4);
    int* counts = (int*)((char*)d_ws + bucket_bytes);        // [N]

    hipMemsetAsync(counts, 0, (size_t)N * sizeof(int), stream);

    edge_bin_kernel<<<(E + 255) / 256, 256, 0, stream>>>(
        pos, cells, species, eidx, eshift, counts, buckets, E);

    node_fused_kernel<<<(N + 3) / 4, 256, 0, stream>>>(
        buckets, counts, semb, mu, sigma, out, N);
}